// Round 2
// baseline (380.991 us; speedup 1.0000x reference)
//
#include <hip/hip_runtime.h>
#include <hip/hip_bf16.h>
#include <math.h>

typedef unsigned short u16;
typedef __bf16 bf16x8 __attribute__((ext_vector_type(8)));
typedef float f32x4 __attribute__((ext_vector_type(4)));
typedef unsigned short u16x8 __attribute__((ext_vector_type(8)));

typedef const __attribute__((address_space(1))) void* gas_ptr;
typedef __attribute__((address_space(3))) void* las_ptr;

__device__ __forceinline__ float bf2f(u16 u) {
    union { unsigned int i; float f; } x;
    x.i = ((unsigned int)u) << 16;
    return x.f;
}
__device__ __forceinline__ u16 f2bf(float f) {
    __hip_bfloat16 h = __float2bfloat16(f);
    return __builtin_bit_cast(u16, h);
}
__device__ __forceinline__ void load_lds16(const void* g, void* l) {
    __builtin_amdgcn_global_load_lds((gas_ptr)g, (las_ptr)l, 16, 0, 0);
}

// ---------------------------------------------------------------------------
// f32 -> bf16 conversion (weights). n divisible by 1024; grid = n/1024 blocks.
// ---------------------------------------------------------------------------
__global__ __launch_bounds__(256) void cvt_k(const float* __restrict__ in,
                                             u16* __restrict__ outp) {
    const int i = blockIdx.x * 256 + threadIdx.x;
    const float4 v = ((const float4*)in)[i];
    ushort4 o;
    o.x = f2bf(v.x); o.y = f2bf(v.y); o.z = f2bf(v.z); o.w = f2bf(v.w);
    ((ushort4*)outp)[i] = o;
}

// ---------------------------------------------------------------------------
// LayerNorm: one block per row (C=512), 256 threads, 2 elems/thread.
// f32 in, bf16 out.
// ---------------------------------------------------------------------------
__global__ __launch_bounds__(256) void ln_k(const float* __restrict__ inp,
                                            const float* __restrict__ gw,
                                            const float* __restrict__ gb,
                                            u16* __restrict__ outp) {
    const int row = blockIdx.x, t = threadIdx.x;
    const float2 v = ((const float2*)(inp + (size_t)row * 512))[t];
    float s = v.x + v.y, q = v.x * v.x + v.y * v.y;
    #pragma unroll
    for (int o = 1; o < 64; o <<= 1) {
        s += __shfl_xor(s, o);
        q += __shfl_xor(q, o);
    }
    __shared__ float rs[4], rq[4];
    const int w = t >> 6;
    if ((t & 63) == 0) { rs[w] = s; rq[w] = q; }
    __syncthreads();
    s = rs[0] + rs[1] + rs[2] + rs[3];
    q = rq[0] + rq[1] + rq[2] + rq[3];
    const float mean = s * (1.0f / 512.0f);
    const float var = q * (1.0f / 512.0f) - mean * mean;
    const float rstd = rsqrtf(var + 1e-5f);
    u16* op = outp + (size_t)row * 512;
    op[2 * t]     = f2bf((v.x - mean) * rstd * gw[2 * t]     + gb[2 * t]);
    op[2 * t + 1] = f2bf((v.y - mean) * rstd * gw[2 * t + 1] + gb[2 * t + 1]);
}

// ---------------------------------------------------------------------------
// GEMM C[m,n] = sum_k A[m,k]*W[n,k] (+epilogue). A:(M,K) bf16, W:(N,K) bf16.
// 128x128 tile, BK=32, 4 waves (2x2), each wave 64x64 via 4x4 mfma 16x16x32.
// EPI 0: out bf16 = acc                      (qkv)
// EPI 1: out f32  = acc + bias + res_f32     (proj->x1, fc2->final)
// EPI 2: out bf16 = gelu(acc + bias)         (fc1)
// ---------------------------------------------------------------------------
template<int EPI>
__global__ __launch_bounds__(256) void gemm_bt(const u16* __restrict__ A,
                                               const u16* __restrict__ W,
                                               const float* __restrict__ bias,
                                               const float* __restrict__ res_f,
                                               void* __restrict__ outp,
                                               int M, int N, int K) {
    __shared__ __bf16 As[2][128 * 32];
    __shared__ __bf16 Bs[2][128 * 32];
    const int t = threadIdx.x;
    const int l = t & 63;
    const int w = t >> 6;
    const int wm = w & 1, wn = w >> 1;
    const int bm = blockIdx.x * 128, bn = blockIdx.y * 128;

    f32x4 acc[4][4] = {};

    auto stage = [&](int buf, int kt) {
        #pragma unroll
        for (int p = 0; p < 2; ++p) {
            const int sb = (p * 256 + t) << 4;     // byte slot in tile
            const int row = sb >> 6;               // 64B per row (BK=32 bf16)
            const int gl = ((sb >> 4) & 3) ^ (row & 3);  // swizzled src group
            const int lbase = p * 2048 + w * 512;  // wave-uniform dest (elems)
            load_lds16(A + (size_t)(bm + row) * K + kt + gl * 8, &As[buf][lbase]);
            load_lds16(W + (size_t)(bn + row) * K + kt + gl * 8, &Bs[buf][lbase]);
        }
    };

    const int nk = K >> 5;
    stage(0, 0);
    __syncthreads();
    for (int s = 0; s < nk; ++s) {
        if (s + 1 < nk) stage((s + 1) & 1, (s + 1) << 5);
        const int buf = s & 1;
        const int r = l & 15, g = l >> 4;
        bf16x8 af[4], bfr[4];
        #pragma unroll
        for (int i = 0; i < 4; ++i) {
            const int ra = wm * 64 + i * 16 + r;
            af[i] = *(const bf16x8*)&As[buf][ra * 32 + ((g ^ (ra & 3)) << 3)];
            const int rb = wn * 64 + i * 16 + r;
            bfr[i] = *(const bf16x8*)&Bs[buf][rb * 32 + ((g ^ (rb & 3)) << 3)];
        }
        #pragma unroll
        for (int i = 0; i < 4; ++i)
            #pragma unroll
            for (int j = 0; j < 4; ++j)
                acc[i][j] = __builtin_amdgcn_mfma_f32_16x16x32_bf16(af[i], bfr[j], acc[i][j], 0, 0, 0);
        __syncthreads();
    }

    #pragma unroll
    for (int i = 0; i < 4; ++i) {
        #pragma unroll
        for (int j = 0; j < 4; ++j) {
            #pragma unroll
            for (int rr = 0; rr < 4; ++rr) {
                const int m = bm + wm * 64 + i * 16 + ((l >> 4) << 2) + rr;
                const int n = bn + wn * 64 + j * 16 + (l & 15);
                float v = acc[i][j][rr];
                const size_t idx = (size_t)m * N + n;
                if (EPI == 0) {
                    ((u16*)outp)[idx] = f2bf(v);
                } else if (EPI == 1) {
                    ((float*)outp)[idx] = v + bias[n] + res_f[idx];
                } else {
                    v += bias[n];
                    v = 0.5f * v * (1.0f + erff(v * 0.70710678118654752f));
                    ((u16*)outp)[idx] = f2bf(v);
                }
            }
        }
    }
}

// ---------------------------------------------------------------------------
// Scores: S[wh,h,r,c] = q.k + 0.1*rpe ; write S fp32; per-block sum|S|.
// grid 2048 = (wh, head). 4 waves, each 16 rows of the 64x64 S tile.
// ---------------------------------------------------------------------------
__global__ __launch_bounds__(256) void scores_k(const u16* __restrict__ qkv,
                                                const float* __restrict__ rpe,
                                                float* __restrict__ Sbuf,
                                                float* __restrict__ Mpart) {
    const int blk = blockIdx.x;
    const int wh = blk >> 3, head = blk & 7;
    const int himg = wh & 63;
    const int t = threadIdx.x, l = t & 63, w = t >> 6;
    __shared__ __bf16 Qs[64 * 64];
    __shared__ __bf16 Ks[64 * 64];

    #pragma unroll
    for (int p = 0; p < 2; ++p) {
        const int sb = (p * 256 + t) << 4;
        const int row = sb >> 7;                    // 128B per row (64 bf16)
        const int gl = ((sb >> 4) & 7) ^ (row & 7); // swizzled src group
        const size_t gsrc = (size_t)(wh * 64 + row) * 1536 + head * 64 + gl * 8;
        const int lbase = p * 2048 + w * 512;
        load_lds16(qkv + gsrc, &Qs[lbase]);
        load_lds16(qkv + gsrc + 512, &Ks[lbase]);
    }
    __syncthreads();

    const int r = l & 15, g = l >> 4;
    f32x4 acc[4] = {};
    #pragma unroll
    for (int h = 0; h < 2; ++h) {
        const int rowq = w * 16 + r;
        bf16x8 aq = *(const bf16x8*)&Qs[rowq * 64 + (((h * 4 + g) ^ (rowq & 7)) << 3)];
        #pragma unroll
        for (int j = 0; j < 4; ++j) {
            const int rowk = j * 16 + r;
            bf16x8 bk = *(const bf16x8*)&Ks[rowk * 64 + (((h * 4 + g) ^ (rowk & 7)) << 3)];
            acc[j] = __builtin_amdgcn_mfma_f32_16x16x32_bf16(aq, bk, acc[j], 0, 0, 0);
        }
    }

    float asum = 0.f;
    const size_t sb_base = (size_t)blk * 4096;
    const size_t rpe_base = (size_t)(himg * 8 + head) * 4096;
    #pragma unroll
    for (int j = 0; j < 4; ++j) {
        #pragma unroll
        for (int rr = 0; rr < 4; ++rr) {
            const int rrow = w * 16 + ((l >> 4) << 2) + rr;
            const int ccol = j * 16 + (l & 15);
            float v = acc[j][rr] + 0.1f * rpe[rpe_base + rrow * 64 + ccol];
            asum += fabsf(v);
            Sbuf[sb_base + rrow * 64 + ccol] = v;
        }
    }
    #pragma unroll
    for (int o = 1; o < 64; o <<= 1) asum += __shfl_xor(asum, o);
    __shared__ float red[4];
    if (l == 0) red[w] = asum;
    __syncthreads();
    if (t == 0) Mpart[blk] = red[0] + red[1] + red[2] + red[3];
}

// ---------------------------------------------------------------------------
// M finalize: M_w = mean|S| per window; M = max(M_w / max_w, 0.5). 1 block.
// ---------------------------------------------------------------------------
__global__ __launch_bounds__(256) void mfinal_k(const float* __restrict__ Mpart,
                                                float* __restrict__ M) {
    const int t = threadIdx.x;
    float m = 0.f;
    #pragma unroll
    for (int h = 0; h < 8; ++h) m += Mpart[t * 8 + h];
    m *= (1.0f / 32768.0f);
    float mx = m;
    #pragma unroll
    for (int o = 1; o < 64; o <<= 1) mx = fmaxf(mx, __shfl_xor(mx, o));
    __shared__ float red[4];
    if ((t & 63) == 0) red[t >> 6] = mx;
    __syncthreads();
    mx = fmaxf(fmaxf(red[0], red[1]), fmaxf(red[2], red[3]));
    M[t] = fmaxf(m / mx, 0.5f);
}

// ---------------------------------------------------------------------------
// Nonlinearity + PV + residual:
// P = (1-cos(S/||S||row * pi/2)) * M ; O = P @ V ; A1 = O + x*(1-M)  (bf16)
// grid 2048 = (wh, head). thread t: row r=t>>2, k-quarter q=t&3.
// ---------------------------------------------------------------------------
__global__ __launch_bounds__(256) void pv_k(const u16* __restrict__ qkv,
                                            const float* __restrict__ Sbuf,
                                            const float* __restrict__ M,
                                            const float* __restrict__ x,
                                            u16* __restrict__ A1) {
    const int blk = blockIdx.x;
    const int wh = blk >> 3, head = blk & 7;
    const int t = threadIdx.x;
    const int r = t >> 2, q = t & 3;
    const float Mw = M[wh];
    const float* Srow = Sbuf + (size_t)blk * 4096 + r * 64 + q * 16;
    float p[16];
    float ss = 0.f;
    #pragma unroll
    for (int i = 0; i < 16; ++i) { p[i] = Srow[i]; ss += p[i] * p[i]; }
    ss += __shfl_xor(ss, 1);
    ss += __shfl_xor(ss, 2);
    const float nrm = fmaxf(sqrtf(ss), 1e-12f);
    const float sc = 1.5707963267948966f / nrm;
    #pragma unroll
    for (int i = 0; i < 16; ++i) p[i] = (1.0f - cosf(p[i] * sc)) * Mw;

    float o[64];
    #pragma unroll
    for (int d = 0; d < 64; ++d) o[d] = 0.f;
    const u16* Vb = qkv + (size_t)(wh * 64) * 1536 + 1024 + head * 64;
    #pragma unroll
    for (int i = 0; i < 16; ++i) {
        const u16* vr = Vb + (size_t)(q * 16 + i) * 1536;
        const float pv = p[i];
        #pragma unroll
        for (int d8 = 0; d8 < 8; ++d8) {
            u16x8 vv = *(const u16x8*)(vr + d8 * 8);
            #pragma unroll
            for (int jj = 0; jj < 8; ++jj) o[d8 * 8 + jj] += pv * bf2f(vv[jj]);
        }
    }
    #pragma unroll
    for (int d = 0; d < 64; ++d) {
        o[d] += __shfl_xor(o[d], 1);
        o[d] += __shfl_xor(o[d], 2);
    }
    const float rf = 1.0f - Mw;
    const int token = wh * 64 + r;
    #pragma unroll
    for (int qq = 0; qq < 4; ++qq) {
        if (q == qq) {
            const size_t base = (size_t)token * 512 + head * 64 + qq * 16;
            u16x8 o0, o1;
            #pragma unroll
            for (int i = 0; i < 8; ++i) {
                o0[i] = f2bf(o[qq * 16 + i]     + x[base + i]     * rf);
                o1[i] = f2bf(o[qq * 16 + 8 + i] + x[base + 8 + i] * rf);
            }
            *(u16x8*)(A1 + base)     = o0;
            *(u16x8*)(A1 + base + 8) = o1;
        }
    }
}

// ---------------------------------------------------------------------------
extern "C" void kernel_launch(void* const* d_in, const int* in_sizes, int n_in,
                              void* d_out, int out_size, void* d_ws, size_t ws_size,
                              hipStream_t stream) {
    (void)in_sizes; (void)n_in; (void)out_size; (void)ws_size;
    const float* x      = (const float*)d_in[0];
    const float* rpe    = (const float*)d_in[1];
    const float* qkv_w  = (const float*)d_in[2];
    const float* proj_w = (const float*)d_in[3];
    const float* proj_b = (const float*)d_in[4];
    const float* n1w    = (const float*)d_in[5];
    const float* n1b    = (const float*)d_in[6];
    const float* n2w    = (const float*)d_in[7];
    const float* n2b    = (const float*)d_in[8];
    const float* fc1w   = (const float*)d_in[9];
    const float* fc1b   = (const float*)d_in[10];
    const float* fc2w   = (const float*)d_in[11];
    const float* fc2b   = (const float*)d_in[12];
    float* out = (float*)d_out;

    char* ws = (char*)d_ws;
    float* Mpart = (float*)ws;                         // 8 KB
    float* Mbuf  = (float*)(ws + 8192);                // 1 KB
    u16* wqkv  = (u16*)(ws + 16384);                   // 1,572,864 B
    u16* wproj = (u16*)(ws + 16384 + 1572864);         // 524,288 B
    u16* wfc1  = (u16*)(ws + 16384 + 2097152);         // 2,097,152 B
    u16* wfc2  = (u16*)(ws + 16384 + 4194304);         // 2,097,152 B
    u16* bufA  = (u16*)(ws + 6307840);                 // 16,777,216 B (img/A1/h1)
    char* R    = ws + 23085056;                        // big overlay region
    u16*   qkvb = (u16*)R;                             // 50,331,648 B
    float* Sbuf = (float*)(R + 50331648);              // 33,554,432 B
    u16*   gbuf = (u16*)R;                             // 67,108,864 B (after S/qkv die)

    // 0. weight conversions f32->bf16
    cvt_k<<<768, 256, 0, stream>>>(qkv_w, wqkv);
    cvt_k<<<256, 256, 0, stream>>>(proj_w, wproj);
    cvt_k<<<1024, 256, 0, stream>>>(fc1w, wfc1);
    cvt_k<<<1024, 256, 0, stream>>>(fc2w, wfc2);
    // 1. LN1: x -> img (bufA, bf16)
    ln_k<<<16384, 256, 0, stream>>>(x, n1w, n1b, bufA);
    // 2. qkv = img @ qkv_w^T  (qkvb bf16)
    gemm_bt<0><<<dim3(128, 12), 256, 0, stream>>>(bufA, wqkv, nullptr, nullptr,
                                                  qkvb, 16384, 1536, 512);
    // 3. scores: S (f32), per-block |S| partials
    scores_k<<<2048, 256, 0, stream>>>(qkvb, rpe, Sbuf, Mpart);
    // 4. M finalize
    mfinal_k<<<1, 256, 0, stream>>>(Mpart, Mbuf);
    // 5. nonlinearity + PV + residual -> A1 (bufA bf16)
    pv_k<<<2048, 256, 0, stream>>>(qkvb, Sbuf, Mbuf, x, bufA);
    // 6. x1 = x + A1 @ proj_w^T + proj_b  -> d_out (f32)
    gemm_bt<1><<<dim3(128, 4), 256, 0, stream>>>(bufA, wproj, proj_b, x,
                                                 out, 16384, 512, 512);
    // 7. LN2: x1 -> h1 (bufA bf16)
    ln_k<<<16384, 256, 0, stream>>>(out, n2w, n2b, bufA);
    // 8. g = gelu(h1 @ fc1_w^T + fc1_b)  (gbuf bf16)
    gemm_bt<2><<<dim3(128, 16), 256, 0, stream>>>(bufA, wfc1, fc1b, nullptr,
                                                  gbuf, 16384, 2048, 512);
    // 9. out = x1 + g @ fc2_w^T + fc2_b  (f32, reads x1 from d_out in place)
    gemm_bt<1><<<dim3(128, 4), 256, 0, stream>>>(gbuf, wfc2, fc2b, out,
                                                 out, 16384, 512, 2048);
}

// Round 3
// 221.055 us; speedup vs baseline: 1.7235x; 1.7235x over previous
//
#include <hip/hip_runtime.h>
#include <hip/hip_bf16.h>
#include <math.h>

typedef unsigned short u16;
typedef __bf16 bf16x8 __attribute__((ext_vector_type(8)));
typedef float f32x4 __attribute__((ext_vector_type(4)));
typedef unsigned short u16x8 __attribute__((ext_vector_type(8)));

typedef const __attribute__((address_space(1))) void* gas_ptr;
typedef __attribute__((address_space(3))) void* las_ptr;

__device__ __forceinline__ float bf2f(u16 u) {
    union { unsigned int i; float f; } x;
    x.i = ((unsigned int)u) << 16;
    return x.f;
}
__device__ __forceinline__ u16 f2bf(float f) {
    __hip_bfloat16 h = __float2bfloat16(f);
    return __builtin_bit_cast(u16, h);
}
__device__ __forceinline__ __bf16 f2bfr(float f) {
    __hip_bfloat16 h = __float2bfloat16(f);
    return __builtin_bit_cast(__bf16, h);
}
__device__ __forceinline__ void load_lds16(const void* g, void* l) {
    __builtin_amdgcn_global_load_lds((gas_ptr)g, (las_ptr)l, 16, 0, 0);
}

// ---------------------------------------------------------------------------
// f32 -> bf16 conversion (weights). grid = n/1024 blocks.
// ---------------------------------------------------------------------------
__global__ __launch_bounds__(256) void cvt_k(const float* __restrict__ in,
                                             u16* __restrict__ outp) {
    const int i = blockIdx.x * 256 + threadIdx.x;
    const float4 v = ((const float4*)in)[i];
    ushort4 o;
    o.x = f2bf(v.x); o.y = f2bf(v.y); o.z = f2bf(v.z); o.w = f2bf(v.w);
    ((ushort4*)outp)[i] = o;
}

// ---------------------------------------------------------------------------
// LayerNorm: one block per row (C=512), 256 threads, 2 elems/thread.
// ---------------------------------------------------------------------------
__global__ __launch_bounds__(256) void ln_k(const float* __restrict__ inp,
                                            const float* __restrict__ gw,
                                            const float* __restrict__ gb,
                                            u16* __restrict__ outp) {
    const int row = blockIdx.x, t = threadIdx.x;
    const float2 v = ((const float2*)(inp + (size_t)row * 512))[t];
    float s = v.x + v.y, q = v.x * v.x + v.y * v.y;
    #pragma unroll
    for (int o = 1; o < 64; o <<= 1) {
        s += __shfl_xor(s, o);
        q += __shfl_xor(q, o);
    }
    __shared__ float rs[4], rq[4];
    const int w = t >> 6;
    if ((t & 63) == 0) { rs[w] = s; rq[w] = q; }
    __syncthreads();
    s = rs[0] + rs[1] + rs[2] + rs[3];
    q = rq[0] + rq[1] + rq[2] + rq[3];
    const float mean = s * (1.0f / 512.0f);
    const float var = q * (1.0f / 512.0f) - mean * mean;
    const float rstd = rsqrtf(var + 1e-5f);
    u16* op = outp + (size_t)row * 512;
    op[2 * t]     = f2bf((v.x - mean) * rstd * gw[2 * t]     + gb[2 * t]);
    op[2 * t + 1] = f2bf((v.y - mean) * rstd * gw[2 * t + 1] + gb[2 * t + 1]);
}

// ---------------------------------------------------------------------------
// GEMM C[m,n] = sum_k A[m,k]*W[n,k] (+epilogue). 128x128 tile, BK=32,
// 4 waves (2x2), each wave 64x64 via 4x4 mfma 16x16x32.
// EPI 0: out bf16 = acc ; EPI 1: out f32 = acc+bias+res ; EPI 2: bf16 gelu.
// ---------------------------------------------------------------------------
template<int EPI>
__global__ __launch_bounds__(256) void gemm_bt(const u16* __restrict__ A,
                                               const u16* __restrict__ W,
                                               const float* __restrict__ bias,
                                               const float* __restrict__ res_f,
                                               void* __restrict__ outp,
                                               int M, int N, int K) {
    __shared__ __bf16 As[2][128 * 32];
    __shared__ __bf16 Bs[2][128 * 32];
    const int t = threadIdx.x;
    const int l = t & 63;
    const int w = t >> 6;
    const int wm = w & 1, wn = w >> 1;
    const int bm = blockIdx.x * 128, bn = blockIdx.y * 128;

    f32x4 acc[4][4] = {};

    auto stage = [&](int buf, int kt) {
        #pragma unroll
        for (int p = 0; p < 2; ++p) {
            const int sb = (p * 256 + t) << 4;
            const int row = sb >> 6;
            const int gl = ((sb >> 4) & 3) ^ (row & 3);
            const int lbase = p * 2048 + w * 512;
            load_lds16(A + (size_t)(bm + row) * K + kt + gl * 8, &As[buf][lbase]);
            load_lds16(W + (size_t)(bn + row) * K + kt + gl * 8, &Bs[buf][lbase]);
        }
    };

    const int nk = K >> 5;
    stage(0, 0);
    __syncthreads();
    for (int s = 0; s < nk; ++s) {
        if (s + 1 < nk) stage((s + 1) & 1, (s + 1) << 5);
        const int buf = s & 1;
        const int r = l & 15, g = l >> 4;
        bf16x8 af[4], bfr[4];
        #pragma unroll
        for (int i = 0; i < 4; ++i) {
            const int ra = wm * 64 + i * 16 + r;
            af[i] = *(const bf16x8*)&As[buf][ra * 32 + ((g ^ (ra & 3)) << 3)];
            const int rb = wn * 64 + i * 16 + r;
            bfr[i] = *(const bf16x8*)&Bs[buf][rb * 32 + ((g ^ (rb & 3)) << 3)];
        }
        #pragma unroll
        for (int i = 0; i < 4; ++i)
            #pragma unroll
            for (int j = 0; j < 4; ++j)
                acc[i][j] = __builtin_amdgcn_mfma_f32_16x16x32_bf16(af[i], bfr[j], acc[i][j], 0, 0, 0);
        __syncthreads();
    }

    #pragma unroll
    for (int i = 0; i < 4; ++i) {
        #pragma unroll
        for (int j = 0; j < 4; ++j) {
            #pragma unroll
            for (int rr = 0; rr < 4; ++rr) {
                const int m = bm + wm * 64 + i * 16 + ((l >> 4) << 2) + rr;
                const int n = bn + wn * 64 + j * 16 + (l & 15);
                float v = acc[i][j][rr];
                const size_t idx = (size_t)m * N + n;
                if (EPI == 0) {
                    ((u16*)outp)[idx] = f2bf(v);
                } else if (EPI == 1) {
                    ((float*)outp)[idx] = v + bias[n] + res_f[idx];
                } else {
                    v += bias[n];
                    v = 0.5f * v * (1.0f + erff(v * 0.70710678118654752f));
                    ((u16*)outp)[idx] = f2bf(v);
                }
            }
        }
    }
}

// ---------------------------------------------------------------------------
// Fused attention per (window, head): S = QK^T + 0.1*rpe ; Mpart = sum|S| ;
// P' = 1 - cos(S/||S||row * pi/2) ; O' = P' @ V  (M factor applied later).
// 4 waves; wave w owns S rows w*16..w*16+15 (full 64 cols in its C/D frags).
// ---------------------------------------------------------------------------
__global__ __launch_bounds__(256) void attn_k(const u16* __restrict__ qkv,
                                              const float* __restrict__ rpe,
                                              float* __restrict__ Mpart,
                                              u16* __restrict__ Obuf) {
    const int blk = blockIdx.x;
    const int wh = blk >> 3, head = blk & 7;
    const int himg = wh & 63;
    const int t = threadIdx.x, l = t & 63, w = t >> 6;
    __shared__ __bf16 Qs[4096];
    __shared__ __bf16 Ks[4096];
    __shared__ __bf16 Vt[4096];   // V transposed [d][k], granule-swizzled
    __shared__ __bf16 Ps[4096];   // per-wave [16][64], granule-swizzled
    __shared__ float red[4];

    // stage Q,K via global_load_lds (linear dest + inverse-swizzled source)
    #pragma unroll
    for (int p = 0; p < 2; ++p) {
        const int sb = (p * 256 + t) << 4;
        const int row = sb >> 7;
        const int gl = ((sb >> 4) & 7) ^ (row & 7);
        const size_t gsrc = (size_t)(wh * 64 + row) * 1536 + head * 64 + gl * 8;
        const int lbase = p * 2048 + w * 512;
        load_lds16(qkv + gsrc, &Qs[lbase]);
        load_lds16(qkv + gsrc + 512, &Ks[lbase]);
    }
    // stage V transposed + swizzled via registers (coalesced global reads)
    {
        const int k = t >> 2, dc = (t & 3) * 16;
        const u16* vr = qkv + (size_t)(wh * 64 + k) * 1536 + 1024 + head * 64 + dc;
        u16x8 v0 = *(const u16x8*)vr;
        u16x8 v1 = *(const u16x8*)(vr + 8);
        const int g = k >> 3, klo = k & 7;
        #pragma unroll
        for (int i = 0; i < 8; ++i) {
            const int d0 = dc + i, d1 = dc + 8 + i;
            Vt[d0 * 64 + ((g ^ (d0 & 7)) << 3) + klo] = __builtin_bit_cast(__bf16, (u16)v0[i]);
            Vt[d1 * 64 + ((g ^ (d1 & 7)) << 3) + klo] = __builtin_bit_cast(__bf16, (u16)v1[i]);
        }
    }
    __syncthreads();

    // QK^T -> S fragments (wave w: rows w*16.., cols 0..63)
    const int r = l & 15, g4 = l >> 4;
    f32x4 acc[4] = {};
    #pragma unroll
    for (int h = 0; h < 2; ++h) {
        const int rowq = w * 16 + r;
        bf16x8 aq = *(const bf16x8*)&Qs[rowq * 64 + (((h * 4 + g4) ^ (rowq & 7)) << 3)];
        #pragma unroll
        for (int j = 0; j < 4; ++j) {
            const int rowk = j * 16 + r;
            bf16x8 bk = *(const bf16x8*)&Ks[rowk * 64 + (((h * 4 + g4) ^ (rowk & 7)) << 3)];
            acc[j] = __builtin_amdgcn_mfma_f32_16x16x32_bf16(aq, bk, acc[j], 0, 0, 0);
        }
    }

    // S + 0.1*rpe ; |S| partial ; per-row sum of squares
    float v[4][4];
    float asum = 0.f;
    float ss[4] = {0.f, 0.f, 0.f, 0.f};
    const size_t rpe_base = (size_t)(himg * 8 + head) * 4096 + (size_t)(w * 16 + g4 * 4) * 64 + r;
    #pragma unroll
    for (int j = 0; j < 4; ++j) {
        #pragma unroll
        for (int rr = 0; rr < 4; ++rr) {
            const float val = acc[j][rr] + 0.1f * rpe[rpe_base + rr * 64 + j * 16];
            v[j][rr] = val;
            asum += fabsf(val);
            ss[rr] += val * val;
        }
    }
    // reduce row sums across the 16 lanes sharing g4 (cols)
    #pragma unroll
    for (int m = 1; m < 16; m <<= 1) {
        #pragma unroll
        for (int rr = 0; rr < 4; ++rr) ss[rr] += __shfl_xor(ss[rr], m);
    }
    float srev[4];
    #pragma unroll
    for (int rr = 0; rr < 4; ++rr)
        srev[rr] = 0.25f / fmaxf(sqrtf(ss[rr]), 1e-12f);   // revolutions scale

    // P' = 1 - cos(S * pi/2 / nrm) via v_cos_f32 (arg in revolutions, |arg|<=0.25)
    // write to wave-local swizzled LDS tile
    #pragma unroll
    for (int j = 0; j < 4; ++j) {
        #pragma unroll
        for (int rr = 0; rr < 4; ++rr) {
            const float pv = 1.0f - __builtin_amdgcn_cosf(v[j][rr] * srev[rr]);
            const int rl = g4 * 4 + rr;
            const int c = j * 16 + r;
            Ps[w * 1024 + rl * 64 + (((c >> 3) ^ (rl & 7)) << 3) + (c & 7)] = f2bfr(pv);
        }
    }

    // PV: O'[rows w*16..][d] = P'(16x64) @ V(64x64); wave-local Ps, shared Vt
    f32x4 oacc[4] = {};
    #pragma unroll
    for (int ks = 0; ks < 2; ++ks) {
        const int ga = ks * 4 + g4;
        bf16x8 pa = *(const bf16x8*)&Ps[w * 1024 + r * 64 + ((ga ^ (r & 7)) << 3)];
        #pragma unroll
        for (int j = 0; j < 4; ++j) {
            const int d = j * 16 + r;
            bf16x8 vb = *(const bf16x8*)&Vt[d * 64 + ((ga ^ (d & 7)) << 3)];
            oacc[j] = __builtin_amdgcn_mfma_f32_16x16x32_bf16(pa, vb, oacc[j], 0, 0, 0);
        }
    }

    // write O' (bf16)
    #pragma unroll
    for (int j = 0; j < 4; ++j) {
        #pragma unroll
        for (int rr = 0; rr < 4; ++rr) {
            const int token = wh * 64 + w * 16 + g4 * 4 + rr;
            Obuf[(size_t)token * 512 + head * 64 + j * 16 + r] = f2bf(oacc[j][rr]);
        }
    }

    // Mpart
    #pragma unroll
    for (int o = 1; o < 64; o <<= 1) asum += __shfl_xor(asum, o);
    if (l == 0) red[w] = asum;
    __syncthreads();
    if (t == 0) Mpart[blk] = red[0] + red[1] + red[2] + red[3];
}

// ---------------------------------------------------------------------------
// M finalize: M_w = mean|S| per window; M = max(M_w / max_w, 0.5). 1 block.
// ---------------------------------------------------------------------------
__global__ __launch_bounds__(256) void mfinal_k(const float* __restrict__ Mpart,
                                                float* __restrict__ M) {
    const int t = threadIdx.x;
    float m = 0.f;
    #pragma unroll
    for (int h = 0; h < 8; ++h) m += Mpart[t * 8 + h];
    m *= (1.0f / 32768.0f);
    float mx = m;
    #pragma unroll
    for (int o = 1; o < 64; o <<= 1) mx = fmaxf(mx, __shfl_xor(mx, o));
    __shared__ float red[4];
    if ((t & 63) == 0) red[t >> 6] = mx;
    __syncthreads();
    mx = fmaxf(fmaxf(red[0], red[1]), fmaxf(red[2], red[3]));
    M[t] = fmaxf(m / mx, 0.5f);
}

// ---------------------------------------------------------------------------
// A1 = M*O' + (1-M)*x   (bf16 out). 8 elems/thread.
// ---------------------------------------------------------------------------
__global__ __launch_bounds__(256) void a1_k(const u16* __restrict__ O,
                                            const float* __restrict__ M,
                                            const float* __restrict__ x,
                                            u16* __restrict__ A1) {
    const size_t i8 = ((size_t)blockIdx.x * 256 + threadIdx.x) * 8;
    const float Mw = M[i8 >> 15];
    const float rf = 1.0f - Mw;
    const u16x8 ov = *(const u16x8*)(O + i8);
    const float4 x0 = *(const float4*)(x + i8);
    const float4 x1 = *(const float4*)(x + i8 + 4);
    u16x8 res;
    res[0] = f2bf(bf2f(ov[0]) * Mw + x0.x * rf);
    res[1] = f2bf(bf2f(ov[1]) * Mw + x0.y * rf);
    res[2] = f2bf(bf2f(ov[2]) * Mw + x0.z * rf);
    res[3] = f2bf(bf2f(ov[3]) * Mw + x0.w * rf);
    res[4] = f2bf(bf2f(ov[4]) * Mw + x1.x * rf);
    res[5] = f2bf(bf2f(ov[5]) * Mw + x1.y * rf);
    res[6] = f2bf(bf2f(ov[6]) * Mw + x1.z * rf);
    res[7] = f2bf(bf2f(ov[7]) * Mw + x1.w * rf);
    *(u16x8*)(A1 + i8) = res;
}

// ---------------------------------------------------------------------------
extern "C" void kernel_launch(void* const* d_in, const int* in_sizes, int n_in,
                              void* d_out, int out_size, void* d_ws, size_t ws_size,
                              hipStream_t stream) {
    (void)in_sizes; (void)n_in; (void)out_size; (void)ws_size;
    const float* x      = (const float*)d_in[0];
    const float* rpe    = (const float*)d_in[1];
    const float* qkv_w  = (const float*)d_in[2];
    const float* proj_w = (const float*)d_in[3];
    const float* proj_b = (const float*)d_in[4];
    const float* n1w    = (const float*)d_in[5];
    const float* n1b    = (const float*)d_in[6];
    const float* n2w    = (const float*)d_in[7];
    const float* n2b    = (const float*)d_in[8];
    const float* fc1w   = (const float*)d_in[9];
    const float* fc1b   = (const float*)d_in[10];
    const float* fc2w   = (const float*)d_in[11];
    const float* fc2b   = (const float*)d_in[12];
    float* out = (float*)d_out;

    char* ws = (char*)d_ws;
    float* Mpart = (float*)ws;                         // 8 KB
    float* Mbuf  = (float*)(ws + 8192);                // 1 KB
    u16* wqkv  = (u16*)(ws + 16384);                   // 1,572,864 B
    u16* wproj = (u16*)(ws + 16384 + 1572864);         // 524,288 B
    u16* wfc1  = (u16*)(ws + 16384 + 2097152);         // 2,097,152 B
    u16* wfc2  = (u16*)(ws + 16384 + 4194304);         // 2,097,152 B
    u16* bufA  = (u16*)(ws + 6307840);                 // 16,777,216 B (img/A1/h1)
    char* R    = ws + 23085056;                        // overlay region
    u16*   qkvb = (u16*)R;                             // 50,331,648 B
    u16*   Obuf = (u16*)(R + 50331648);                // 16,777,216 B
    u16*   gbuf = (u16*)R;                             // 67,108,864 B (qkv+O dead)

    // 0. weight conversions f32->bf16
    cvt_k<<<768, 256, 0, stream>>>(qkv_w, wqkv);
    cvt_k<<<256, 256, 0, stream>>>(proj_w, wproj);
    cvt_k<<<1024, 256, 0, stream>>>(fc1w, wfc1);
    cvt_k<<<1024, 256, 0, stream>>>(fc2w, wfc2);
    // 1. LN1: x -> img (bufA, bf16)
    ln_k<<<16384, 256, 0, stream>>>(x, n1w, n1b, bufA);
    // 2. qkv = img @ qkv_w^T  (qkvb bf16)
    gemm_bt<0><<<dim3(128, 12), 256, 0, stream>>>(bufA, wqkv, nullptr, nullptr,
                                                  qkvb, 16384, 1536, 512);
    // 3. fused attention: O' (no M factor) + Mpart
    attn_k<<<2048, 256, 0, stream>>>(qkvb, rpe, Mpart, Obuf);
    // 4. M finalize
    mfinal_k<<<1, 256, 0, stream>>>(Mpart, Mbuf);
    // 5. A1 = M*O' + (1-M)*x  (bufA bf16)
    a1_k<<<4096, 256, 0, stream>>>(Obuf, Mbuf, x, bufA);
    // 6. x1 = x + A1 @ proj_w^T + proj_b  -> d_out (f32)
    gemm_bt<1><<<dim3(128, 4), 256, 0, stream>>>(bufA, wproj, proj_b, x,
                                                 out, 16384, 512, 512);
    // 7. LN2: x1 -> h1 (bufA bf16)
    ln_k<<<16384, 256, 0, stream>>>(out, n2w, n2b, bufA);
    // 8. g = gelu(h1 @ fc1_w^T + fc1_b)  (gbuf bf16)
    gemm_bt<2><<<dim3(128, 16), 256, 0, stream>>>(bufA, wfc1, fc1b, nullptr,
                                                  gbuf, 16384, 2048, 512);
    // 9. out = x1 + g @ fc2_w^T + fc2_b  (f32, in-place read of x1)
    gemm_bt<1><<<dim3(128, 4), 256, 0, stream>>>(gbuf, wfc2, fc2b, out,
                                                 out, 16384, 512, 2048);
}